// Round 1
// baseline (805.348 us; speedup 1.0000x reference)
//
#include <hip/hip_runtime.h>

// Problem constants (from reference setup_inputs)
constexpr int BB = 16;      // batch
constexpr int D  = 2048;
constexpr int U  = 37;
constexpr long long DD = (long long)D * D;   // 4,194,304

constexpr int TPB = 256;
constexpr int BLOCKS_PER_U = 128;                       // 4736 blocks total
constexpr int F4_PER_CHUNK = (int)(DD / BLOCKS_PER_U / 4); // 8192 float4 per chunk
constexpr int ITERS = F4_PER_CHUNK / TPB;               // 32

// Kernel A: base[u] = sum_ij relu(matrix[ij]) * weight[u,ij]
// Streaming, float4-vectorized, memory-bound on weight (620 MB).
__global__ __launch_bounds__(TPB) void base_reduce_kernel(
    const float* __restrict__ matrix,
    const float* __restrict__ weight,
    float* __restrict__ base)   // base: U floats in d_ws, pre-zeroed
{
    const int chunk = blockIdx.x;
    const int u     = blockIdx.y;

    const float4* __restrict__ m4 = (const float4*)matrix;
    const float4* __restrict__ w4 = (const float4*)(weight + (long long)u * DD);

    long long idx = (long long)chunk * F4_PER_CHUNK + threadIdx.x;

    float acc = 0.f;
#pragma unroll 8
    for (int it = 0; it < ITERS; ++it) {
        float4 m = m4[idx + (long long)it * TPB];
        float4 w = w4[idx + (long long)it * TPB];
        acc = fmaf(fmaxf(m.x, 0.f), w.x, acc);
        acc = fmaf(fmaxf(m.y, 0.f), w.y, acc);
        acc = fmaf(fmaxf(m.z, 0.f), w.z, acc);
        acc = fmaf(fmaxf(m.w, 0.f), w.w, acc);
    }

    // wave64 reduce
#pragma unroll
    for (int off = 32; off > 0; off >>= 1)
        acc += __shfl_down(acc, off, 64);

    __shared__ float smem[TPB / 64];
    if ((threadIdx.x & 63) == 0) smem[threadIdx.x >> 6] = acc;
    __syncthreads();
    if (threadIdx.x == 0) {
        float t = 0.f;
#pragma unroll
        for (int w = 0; w < TPB / 64; ++w) t += smem[w];
        atomicAdd(&base[u], t);   // 4736 atomics total across 37 addresses
    }
}

// Kernel B: out[b,u] = base[u] + bias[u]
//                    + sum_i (relu(m_ii * x_bi) - relu(m_ii)) * w[u,i,i]
__global__ __launch_bounds__(TPB) void diag_finish_kernel(
    const float* __restrict__ inputs,
    const float* __restrict__ matrix,
    const float* __restrict__ weight,
    const float* __restrict__ bias,
    const float* __restrict__ base,
    float* __restrict__ out)
{
    const int u = blockIdx.x;
    const int b = blockIdx.y;

    float acc = 0.f;
    for (int i = threadIdx.x; i < D; i += TPB) {
        float m = matrix[(long long)i * (D + 1)];
        float w = weight[(long long)u * DD + (long long)i * (D + 1)];
        float x = inputs[b * D + i];
        acc += (fmaxf(m * x, 0.f) - fmaxf(m, 0.f)) * w;
    }

#pragma unroll
    for (int off = 32; off > 0; off >>= 1)
        acc += __shfl_down(acc, off, 64);

    __shared__ float smem[TPB / 64];
    if ((threadIdx.x & 63) == 0) smem[threadIdx.x >> 6] = acc;
    __syncthreads();
    if (threadIdx.x == 0) {
        float t = 0.f;
#pragma unroll
        for (int w = 0; w < TPB / 64; ++w) t += smem[w];
        out[b * U + u] = t + base[u] + bias[u];
    }
}

extern "C" void kernel_launch(void* const* d_in, const int* in_sizes, int n_in,
                              void* d_out, int out_size, void* d_ws, size_t ws_size,
                              hipStream_t stream) {
    const float* inputs = (const float*)d_in[0];   // (B, D)
    const float* matrix = (const float*)d_in[1];   // (D, D)
    const float* weight = (const float*)d_in[2];   // (U, D, D)
    const float* bias   = (const float*)d_in[3];   // (U,)
    float* out  = (float*)d_out;                   // (B, U) f32
    float* base = (float*)d_ws;                    // U floats scratch

    // d_ws is re-poisoned to 0xAA before every call — zero it (graph-capture safe).
    hipMemsetAsync(base, 0, U * sizeof(float), stream);

    base_reduce_kernel<<<dim3(BLOCKS_PER_U, U), TPB, 0, stream>>>(matrix, weight, base);
    diag_finish_kernel<<<dim3(U, BB), TPB, 0, stream>>>(inputs, matrix, weight, bias, base, out);
}

// Round 2
// 802.007 us; speedup vs baseline: 1.0042x; 1.0042x over previous
//
#include <hip/hip_runtime.h>

// Problem constants (from reference setup_inputs)
constexpr int BB = 16;      // batch
constexpr int D  = 2048;
constexpr int U  = 37;
constexpr long long DD = (long long)D * D;   // 4,194,304 elements, 16 MB

constexpr int TPB = 256;
constexpr int C   = 512;                          // chunks over the (i,j) space
constexpr int F4_PER_BLOCK  = (int)(DD / 4 / C);  // 2048 float4 per chunk (32 KB)
constexpr int F4_PER_THREAD = F4_PER_BLOCK / TPB; // 8 float4 per thread

// Kernel A: partial[u, c] = sum_{ij in chunk c} relu(matrix[ij]) * weight[u, ij]
// Each block reads its matrix chunk ONCE into registers (relu pre-applied),
// then streams all 37 weight planes through it. Weight traffic: 620 MB once.
__global__ __launch_bounds__(TPB) void base_reduce_kernel(
    const float* __restrict__ matrix,
    const float* __restrict__ weight,
    float* __restrict__ partial)   // (U, C) in d_ws, fully written before read
{
    const int c = blockIdx.x;
    const long long base4 = (long long)c * F4_PER_BLOCK + threadIdx.x;
    const float4* __restrict__ m4 = (const float4*)matrix;

    // Cache relu(matrix chunk) in registers: 8 x float4 = 32 VGPRs.
    float4 m[F4_PER_THREAD];
#pragma unroll
    for (int it = 0; it < F4_PER_THREAD; ++it) {
        float4 t = m4[base4 + (long long)it * TPB];
        m[it].x = fmaxf(t.x, 0.f);
        m[it].y = fmaxf(t.y, 0.f);
        m[it].z = fmaxf(t.z, 0.f);
        m[it].w = fmaxf(t.w, 0.f);
    }

    __shared__ float lpart[U];
    if (threadIdx.x < U) lpart[threadIdx.x] = 0.f;
    __syncthreads();

    for (int u = 0; u < U; ++u) {
        const float4* __restrict__ w4 = (const float4*)(weight + (long long)u * DD);
        float acc = 0.f;
#pragma unroll
        for (int it = 0; it < F4_PER_THREAD; ++it) {
            float4 w = w4[base4 + (long long)it * TPB];
            acc = fmaf(m[it].x, w.x, acc);
            acc = fmaf(m[it].y, w.y, acc);
            acc = fmaf(m[it].z, w.z, acc);
            acc = fmaf(m[it].w, w.w, acc);
        }
        // wave64 reduce
#pragma unroll
        for (int off = 32; off > 0; off >>= 1)
            acc += __shfl_down(acc, off, 64);
        if ((threadIdx.x & 63) == 0)
            atomicAdd(&lpart[u], acc);   // LDS atomic, 4 waves/block
    }

    __syncthreads();
    if (threadIdx.x < U)
        partial[(long long)threadIdx.x * C + c] = lpart[threadIdx.x];
}

// Kernel B: out[b,u] = bias[u] + sum_c partial[u,c]
//                    + sum_i (relu(m_ii * x_bi) - relu(m_ii)) * w[u,i,i]
__global__ __launch_bounds__(TPB) void diag_finish_kernel(
    const float* __restrict__ inputs,
    const float* __restrict__ matrix,
    const float* __restrict__ weight,
    const float* __restrict__ bias,
    const float* __restrict__ partial,
    float* __restrict__ out)
{
    const int u = blockIdx.x;
    const int b = blockIdx.y;

    float acc = 0.f;
    for (int i = threadIdx.x; i < D; i += TPB) {
        float mm = matrix[(long long)i * (D + 1)];
        float w  = weight[(long long)u * DD + (long long)i * (D + 1)];
        float x  = inputs[b * D + i];
        acc += (fmaxf(mm * x, 0.f) - fmaxf(mm, 0.f)) * w;
    }
    for (int c = threadIdx.x; c < C; c += TPB)
        acc += partial[(long long)u * C + c];

#pragma unroll
    for (int off = 32; off > 0; off >>= 1)
        acc += __shfl_down(acc, off, 64);

    __shared__ float smem[TPB / 64];
    if ((threadIdx.x & 63) == 0) smem[threadIdx.x >> 6] = acc;
    __syncthreads();
    if (threadIdx.x == 0) {
        float t = 0.f;
#pragma unroll
        for (int w = 0; w < TPB / 64; ++w) t += smem[w];
        out[b * U + u] = t + bias[u];
    }
}

extern "C" void kernel_launch(void* const* d_in, const int* in_sizes, int n_in,
                              void* d_out, int out_size, void* d_ws, size_t ws_size,
                              hipStream_t stream) {
    const float* inputs = (const float*)d_in[0];   // (B, D)
    const float* matrix = (const float*)d_in[1];   // (D, D)
    const float* weight = (const float*)d_in[2];   // (U, D, D)
    const float* bias   = (const float*)d_in[3];   // (U,)
    float* out     = (float*)d_out;                // (B, U) f32
    float* partial = (float*)d_ws;                 // (U, C) floats scratch

    base_reduce_kernel<<<dim3(C), TPB, 0, stream>>>(matrix, weight, partial);
    diag_finish_kernel<<<dim3(U, BB), TPB, 0, stream>>>(inputs, matrix, weight, bias,
                                                        partial, out);
}